// Round 13
// baseline (709.353 us; speedup 1.0000x reference)
//
#include <hip/hip_runtime.h>

#define N_NODES 8000
#define FEAT 64
#define HID 128
#define LOOKBACK 12
#define CAP 64
#define NBLK 256
#define NGRP 500

// ---------------- zero counters + barrier words ----------------
__global__ __launch_bounds__(256)
void zero_kernel(int* __restrict__ cnt, unsigned* __restrict__ bar) {
    int g = blockIdx.x * 256 + threadIdx.x;
    if (g < N_NODES) cnt[g] = 0;
    if (g < 32) bar[g] = 0u;
}

// ---------------- adjacency extraction: grid-strided (R12, verified) ----------------
__global__ __launch_bounds__(256)
void build_adj_kernel(const float* __restrict__ adj, int* __restrict__ cnt,
                      int* __restrict__ lists) {
    const long NQ = (long)N_NODES * N_NODES / 4;
    const long STRIDE = 2048L * 256;
    for (long q = (long)blockIdx.x * 256 + threadIdx.x; q < NQ; q += STRIDE) {
        float4 w = *reinterpret_cast<const float4*>(adj + 4 * q);
        if (w.x != 0.0f || w.y != 0.0f || w.z != 0.0f || w.w != 0.0f) {
            int i  = (int)(q / (N_NODES / 4));
            int j0 = (int)(q % (N_NODES / 4)) * 4;
            float wv[4] = {w.x, w.y, w.z, w.w};
            #pragma unroll
            for (int c = 0; c < 4; ++c) {
                if (wv[c] != 0.0f) {
                    int j = j0 + c;
                    int p = atomicAdd(&cnt[j], 1);
                    if (p < CAP) lists[(long)j * CAP + p] = i;
                }
            }
        }
    }
}

// ---------------- software grid barrier v2: SYSTEM-scope RMW poll ----------------
// R10's failure: AGENT-scope acquire LOADS polled a stale per-XCD L2 line forever
// (886us = 7 barriers x 2^23 iters x ~15ns). RMW atomics serialize at the
// coherent point and cannot read stale data. 256 blocks @2 slots/CU needs only
// 128 CUs -> co-residency guaranteed with huge margin.
__device__ __forceinline__ void gsync(unsigned* __restrict__ bar) {
    __syncthreads();
    if (threadIdx.x == 0) {
        __threadfence_system();
        unsigned g = __hip_atomic_fetch_add(&bar[16], 0u, __ATOMIC_ACQUIRE,
                                            __HIP_MEMORY_SCOPE_SYSTEM);
        unsigned a = __hip_atomic_fetch_add(&bar[0], 1u, __ATOMIC_ACQ_REL,
                                            __HIP_MEMORY_SCOPE_SYSTEM);
        if (a == (unsigned)(NBLK - 1)) {
            __hip_atomic_store(&bar[0], 0u, __ATOMIC_RELAXED, __HIP_MEMORY_SCOPE_SYSTEM);
            __hip_atomic_fetch_add(&bar[16], 1u, __ATOMIC_RELEASE, __HIP_MEMORY_SCOPE_SYSTEM);
        } else {
            long it = 0;
            while (__hip_atomic_fetch_add(&bar[16], 0u, __ATOMIC_ACQUIRE,
                                          __HIP_MEMORY_SCOPE_SYSTEM) == g) {
                if (++it > (1L << 13)) break;   // anti-hang bail; never hit if coherent
            }
        }
    }
    __syncthreads();
    __threadfence();
}

// ---------------- persistent mega-kernel: prep + init + 3 Euler steps ----------------
// 256 blocks x 256 threads; each block owns node-groups {bid, bid+256} (<500).
// Phase bodies verbatim from R12 kernels -> bit-identical output.
__global__ __launch_bounds__(256, 2)
void mega_kernel(const float* __restrict__ tspan, const float* __restrict__ x,
                 const float* __restrict__ We1, const float* __restrict__ be1,
                 const float* __restrict__ We2, const float* __restrict__ be2,
                 const float* __restrict__ Wf1, const float* __restrict__ bf1,
                 const float* __restrict__ Wf2, const float* __restrict__ bf2,
                 const float* __restrict__ Wl1, const float* __restrict__ bl1,
                 const float* __restrict__ Wr1,
                 const float* __restrict__ Wl2, const float* __restrict__ bl2,
                 const float* __restrict__ Wr2,
                 int* __restrict__ cnt, int* __restrict__ lists,
                 float* __restrict__ degf,
                 float* __restrict__ Ws1, float* __restrict__ Wc2,
                 float* __restrict__ pl, float* __restrict__ q,
                 float* __restrict__ out, unsigned* __restrict__ bar) {
    __shared__ float v[16][132];
    __shared__ float rr[16][132];
    __shared__ float tt[16][132];
    __shared__ float xsl[16][68];
    __shared__ float wbuf[64 * 128];
    const int tid = threadIdx.x;
    const int bid = blockIdx.x;

    // ======== phase A: sort lists + deg + weight stacking + init encoder ========
    {
        const int wv = tid >> 6, lane = tid & 63;
        #pragma unroll 1
        for (int r = 0; r < 8; ++r) {
            const int n = (bid * 4 + wv) + 1024 * r;
            if (n < N_NODES) {
                int m = cnt[n]; if (m > CAP) m = CAP;
                int val = (lane < m) ? lists[(long)n * CAP + lane] : 0x7FFFFFFF;
                #pragma unroll
                for (int k = 2; k <= 64; k <<= 1) {
                    #pragma unroll
                    for (int j = k >> 1; j > 0; j >>= 1) {
                        int other = __shfl_xor(val, j);
                        bool keepMin = (((lane & j) == 0) == ((lane & k) == 0));
                        int mn = val < other ? val : other;
                        int mx = val < other ? other : val;
                        val = keepMin ? mn : mx;
                    }
                }
                lists[(long)n * CAP + lane] = val;
                if (lane == 0) { cnt[n] = m; degf[n] = (float)(m > 0 ? m : 1); }
            }
        }
        const int gid = bid * 256 + tid;        // 65536 threads
        if (gid < 128 * 128) {                  // Ws1[k][j] = [Wl1;Wr1]
            int k = gid >> 7, j = gid & 127;
            Ws1[gid] = (k < 64) ? Wl1[k * 128 + j] : Wr1[(k - 64) * 128 + j];
        } else if (gid < 2 * 128 * 128) {       // Wc2[k][j] = [Wl2 | Wr2]
            int w = gid - 128 * 128;
            int k = w >> 7, j = w & 127;
            Wc2[w] = (j < 64) ? Wl2[k * 64 + j] : Wr2[k * 64 + (j - 64)];
        }
        // ---- init encoder (tables in wbuf), 2 rounds of 4 elems ----
        float* sW1T = wbuf;
        float* sB1  = wbuf + 1536;
        float* sW2  = wbuf + 1664;
        __syncthreads();
        for (int e = tid; e < HID * LOOKBACK; e += 256) {
            int l = e / HID, hh = e % HID;
            sW1T[hh * LOOKBACK + l] = We1[e];
        }
        for (int e = tid; e < HID; e += 256) { sB1[e] = be1[e]; sW2[e] = We2[e]; }
        __syncthreads();
        #pragma unroll 1
        for (int r = 0; r < 2; ++r) {
            int g = (bid * 256 + tid + r * 65536) * 4;
            if (g < N_NODES * FEAT) {
                float xv[4][LOOKBACK];
                #pragma unroll
                for (int l = 0; l < LOOKBACK; ++l) {
                    float4 vv = *reinterpret_cast<const float4*>(x + (long)l * N_NODES * FEAT + g);
                    xv[0][l] = vv.x; xv[1][l] = vv.y; xv[2][l] = vv.z; xv[3][l] = vv.w;
                }
                float b2 = be2[0];
                float acc[4] = {b2, b2, b2, b2};
                for (int hh = 0; hh < HID; ++hh) {
                    float s0 = sB1[hh], s1 = s0, s2 = s0, s3 = s0;
                    #pragma unroll
                    for (int l = 0; l < LOOKBACK; ++l) {
                        float w = sW1T[hh * LOOKBACK + l];
                        s0 += xv[0][l] * w; s1 += xv[1][l] * w;
                        s2 += xv[2][l] * w; s3 += xv[3][l] * w;
                    }
                    float w2 = sW2[hh];
                    acc[0] += fmaxf(s0, 0.0f) * w2; acc[1] += fmaxf(s1, 0.0f) * w2;
                    acc[2] += fmaxf(s2, 0.0f) * w2; acc[3] += fmaxf(s3, 0.0f) * w2;
                }
                float4 o = {acc[0], acc[1], acc[2], acc[3]};
                *reinterpret_cast<float4*>(out + g) = o;
            }
        }
    }
    gsync(bar);

    // ======== 3 Euler steps ========
    const int ln = tid >> 4, jg = tid & 15;
    const int c0 = jg * 4;
    for (int s = 0; s < 3; ++s) {
        const float* h     = out + (long)s * N_NODES * FEAT;
        float*       hnext = out + (long)(s + 1) * N_NODES * FEAT;
        // ===== sageproj phase over owned groups =====
        #pragma unroll 1
        for (int gi = bid; gi < NGRP; gi += NBLK) {
            const int n = gi * 16 + ln;
            {   // gather
                const int m = cnt[n];
                const int* l = lists + (long)n * CAP;
                const float inv = 1.0f / degf[n];
                float4 a = {0, 0, 0, 0};
                for (int e = 0; e < m; ++e) {
                    float4 b = *reinterpret_cast<const float4*>(h + (long)l[e] * FEAT + c0);
                    a.x += b.x; a.y += b.y; a.z += b.z; a.w += b.w;
                }
                float4 av = {a.x * inv, a.y * inv, a.z * inv, a.w * inv};
                *reinterpret_cast<float4*>(&v[ln][c0]) = av;
                *reinterpret_cast<float4*>(&v[ln][64 + c0]) =
                    *reinterpret_cast<const float4*>(h + (long)n * FEAT + c0);
            }
            // P1
            {
                float4 b0 = *reinterpret_cast<const float4*>(bl1 + c0);
                float4 b1 = *reinterpret_cast<const float4*>(bl1 + 64 + c0);
                float A0[4] = {b0.x, b0.y, b0.z, b0.w};
                float A1[4] = {b1.x, b1.y, b1.z, b1.w};
                for (int kc = 0; kc < 2; ++kc) {
                    __syncthreads();
                    for (int e = tid; e < 2048; e += 256)
                        *(reinterpret_cast<float4*>(wbuf) + e) =
                            *(reinterpret_cast<const float4*>(Ws1 + kc * 8192) + e);
                    __syncthreads();
                    #pragma unroll 4
                    for (int k = 0; k < 64; ++k) {
                        float a = v[ln][kc * 64 + k];
                        float4 w0 = *reinterpret_cast<const float4*>(&wbuf[k * 128 + c0]);
                        float4 w1 = *reinterpret_cast<const float4*>(&wbuf[k * 128 + 64 + c0]);
                        A0[0] += a * w0.x; A0[1] += a * w0.y; A0[2] += a * w0.z; A0[3] += a * w0.w;
                        A1[0] += a * w1.x; A1[1] += a * w1.y; A1[2] += a * w1.z; A1[3] += a * w1.w;
                    }
                }
                float4 o0 = {fmaxf(A0[0],0.f), fmaxf(A0[1],0.f), fmaxf(A0[2],0.f), fmaxf(A0[3],0.f)};
                float4 o1 = {fmaxf(A1[0],0.f), fmaxf(A1[1],0.f), fmaxf(A1[2],0.f), fmaxf(A1[3],0.f)};
                *reinterpret_cast<float4*>(&rr[ln][c0]) = o0;
                *reinterpret_cast<float4*>(&rr[ln][64 + c0]) = o1;
            }
            // P2
            {
                float4 b0 = *reinterpret_cast<const float4*>(bf1 + c0);
                float4 b1 = *reinterpret_cast<const float4*>(bf1 + 64 + c0);
                float A0[4] = {b0.x, b0.y, b0.z, b0.w};
                float A1[4] = {b1.x, b1.y, b1.z, b1.w};
                __syncthreads();
                for (int e = tid; e < 2048; e += 256)
                    *(reinterpret_cast<float4*>(wbuf) + e) =
                        *(reinterpret_cast<const float4*>(Wf1) + e);
                __syncthreads();
                #pragma unroll 4
                for (int k = 0; k < 64; ++k) {
                    float a = v[ln][64 + k];
                    float4 w0 = *reinterpret_cast<const float4*>(&wbuf[k * 128 + c0]);
                    float4 w1 = *reinterpret_cast<const float4*>(&wbuf[k * 128 + 64 + c0]);
                    A0[0] += a * w0.x; A0[1] += a * w0.y; A0[2] += a * w0.z; A0[3] += a * w0.w;
                    A1[0] += a * w1.x; A1[1] += a * w1.y; A1[2] += a * w1.z; A1[3] += a * w1.w;
                }
                float4 o0 = {fmaxf(A0[0],0.f), fmaxf(A0[1],0.f), fmaxf(A0[2],0.f), fmaxf(A0[3],0.f)};
                float4 o1 = {fmaxf(A1[0],0.f), fmaxf(A1[1],0.f), fmaxf(A1[2],0.f), fmaxf(A1[3],0.f)};
                *reinterpret_cast<float4*>(&tt[ln][c0]) = o0;
                *reinterpret_cast<float4*>(&tt[ln][64 + c0]) = o1;
            }
            // P3
            {
                float4 b0 = *reinterpret_cast<const float4*>(bf2 + c0);
                float X[4] = {b0.x, b0.y, b0.z, b0.w};
                __syncthreads();
                for (int e = tid; e < 2048; e += 256)
                    *(reinterpret_cast<float4*>(wbuf) + e) =
                        *(reinterpret_cast<const float4*>(Wf2) + e);
                __syncthreads();
                #pragma unroll 4
                for (int k = 0; k < 128; ++k) {
                    float a = tt[ln][k];
                    float4 w = *reinterpret_cast<const float4*>(&wbuf[k * 64 + c0]);
                    X[0] += a * w.x; X[1] += a * w.y; X[2] += a * w.z; X[3] += a * w.w;
                }
                float4 o = {X[0], X[1], X[2], X[3]};
                *reinterpret_cast<float4*>(&xsl[ln][c0]) = o;
            }
            // P4
            {
                float P0[4] = {0, 0, 0, 0};
                float P1[4] = {0, 0, 0, 0};
                for (int kc = 0; kc < 2; ++kc) {
                    __syncthreads();
                    for (int e = tid; e < 2048; e += 256)
                        *(reinterpret_cast<float4*>(wbuf) + e) =
                            *(reinterpret_cast<const float4*>(Wc2 + kc * 8192) + e);
                    __syncthreads();
                    #pragma unroll 4
                    for (int k = 0; k < 64; ++k) {
                        float a = rr[ln][kc * 64 + k];
                        float4 w0 = *reinterpret_cast<const float4*>(&wbuf[k * 128 + c0]);
                        float4 w1 = *reinterpret_cast<const float4*>(&wbuf[k * 128 + 64 + c0]);
                        P0[0] += a * w0.x; P0[1] += a * w0.y; P0[2] += a * w0.z; P0[3] += a * w0.w;
                        P1[0] += a * w1.x; P1[1] += a * w1.y; P1[2] += a * w1.z; P1[3] += a * w1.w;
                    }
                }
                float4 op = {P0[0], P0[1], P0[2], P0[3]};
                *reinterpret_cast<float4*>(pl + (long)n * FEAT + c0) = op;
                float4 bv = *reinterpret_cast<const float4*>(bl2 + c0);
                float4 oq = {P1[0] + bv.x + xsl[ln][c0 + 0],
                             P1[1] + bv.y + xsl[ln][c0 + 1],
                             P1[2] + bv.z + xsl[ln][c0 + 2],
                             P1[3] + bv.w + xsl[ln][c0 + 3]};
                *reinterpret_cast<float4*>(q + (long)n * FEAT + c0) = oq;
            }
        }
        gsync(bar);
        // ===== epi phase over owned groups =====
        #pragma unroll 1
        for (int gi = bid; gi < NGRP; gi += NBLK) {
            const int n = gi * 16 + ln;
            const int m = cnt[n];
            const int* l = lists + (long)n * CAP;
            const float inv = 1.0f / degf[n];
            float4 a = {0, 0, 0, 0};
            for (int e = 0; e < m; ++e) {
                float4 b = *reinterpret_cast<const float4*>(pl + (long)l[e] * FEAT + c0);
                a.x += b.x; a.y += b.y; a.z += b.z; a.w += b.w;
            }
            const float dt = tspan[s + 1] - tspan[s];
            float4 qv = *reinterpret_cast<const float4*>(q + (long)n * FEAT + c0);
            float4 hv = *reinterpret_cast<const float4*>(h + (long)n * FEAT + c0);
            float s0 = qv.x + a.x * inv, s1 = qv.y + a.y * inv;
            float s2 = qv.z + a.z * inv, s3 = qv.w + a.w * inv;
            s0 = fminf(fmaxf(s0, -1000.f), 1000.f); s1 = fminf(fmaxf(s1, -1000.f), 1000.f);
            s2 = fminf(fmaxf(s2, -1000.f), 1000.f); s3 = fminf(fmaxf(s3, -1000.f), 1000.f);
            float4 o = {hv.x + dt * s0, hv.y + dt * s1, hv.z + dt * s2, hv.w + dt * s3};
            *reinterpret_cast<float4*>(hnext + (long)n * FEAT + c0) = o;
        }
        if (s < 2) gsync(bar);
    }
}

extern "C" void kernel_launch(void* const* d_in, const int* in_sizes, int n_in,
                              void* d_out, int out_size, void* d_ws, size_t ws_size,
                              hipStream_t stream) {
    const float* tspan = (const float*)d_in[0];
    const float* x     = (const float*)d_in[1];
    const float* adj   = (const float*)d_in[2];
    const float* We1   = (const float*)d_in[3];
    const float* be1   = (const float*)d_in[4];
    const float* We2   = (const float*)d_in[5];
    const float* be2   = (const float*)d_in[6];
    const float* Wf1   = (const float*)d_in[7];
    const float* bf1   = (const float*)d_in[8];
    const float* Wf2   = (const float*)d_in[9];
    const float* bf2   = (const float*)d_in[10];
    const float* Wl1   = (const float*)d_in[11];
    const float* bl1   = (const float*)d_in[12];
    const float* Wr1   = (const float*)d_in[13];
    const float* Wl2   = (const float*)d_in[14];
    const float* bl2   = (const float*)d_in[15];
    const float* Wr2   = (const float*)d_in[16];
    float* out = (float*)d_out;

    // workspace layout (bytes)
    char* ws = (char*)d_ws;
    int*      lists = (int*)     (ws + 0);           // 2,048,000
    int*      cnt   = (int*)     (ws + 2048000);     // 32,000
    float*    degf  = (float*)   (ws + 2080000);     // 32,000
    float*    Ws1   = (float*)   (ws + 2112000);     // 65,536
    float*    Wc2   = (float*)   (ws + 2177536);     // 65,536
    float*    pl    = (float*)   (ws + 2243072);     // 2,048,000
    float*    q     = (float*)   (ws + 4291072);     // 2,048,000
    unsigned* bar   = (unsigned*)(ws + 6339072);     // 128
    // total 6,339,200 bytes

    zero_kernel<<<32, 256, 0, stream>>>(cnt, bar);
    build_adj_kernel<<<2048, 256, 0, stream>>>(adj, cnt, lists);
    mega_kernel<<<NBLK, 256, 0, stream>>>(tspan, x, We1, be1, We2, be2,
                                          Wf1, bf1, Wf2, bf2,
                                          Wl1, bl1, Wr1, Wl2, bl2, Wr2,
                                          cnt, lists, degf, Ws1, Wc2,
                                          pl, q, out, bar);
}